// Round 1
// baseline (1048.029 us; speedup 1.0000x reference)
//
#include <hip/hip_runtime.h>

#define LN_EPS 1e-5f

// ---------------------------------------------------------------------------
// Kernel 1/3: gather + mean aggregation.
// dst = repeat(arange(M), fan) -> target t owns edges [t*fan, (t+1)*fan), and
// cnt == fan exactly. One wave (64 lanes) per target row; lane handles float4
// (64*4 = 256 features). Writes A[t] = [ mean_agg (256) | x[tlid[t]] (256) ].
// ---------------------------------------------------------------------------
__global__ __launch_bounds__(256) void gather_mean_kernel(
    const float* __restrict__ X,      // [*, 256]
    const int* __restrict__ src,      // [M*fan]
    const int* __restrict__ tlid,     // [M]
    float* __restrict__ A,            // [M, 512]
    int M, int fan, float inv_fan)
{
    const int wave = threadIdx.x >> 6;
    const int lane = threadIdx.x & 63;
    const long t = (long)blockIdx.x * 4 + wave;
    if (t >= M) return;

    const int* es = src + t * (long)fan;
    float a0 = 0.f, a1 = 0.f, a2 = 0.f, a3 = 0.f;
    for (int e = 0; e < fan; ++e) {
        const long s = es[e];  // wave-uniform -> scalar load
        const float4 v = *(const float4*)(X + s * 256 + lane * 4);
        a0 += v.x; a1 += v.y; a2 += v.z; a3 += v.w;
    }
    float4 o;
    o.x = a0 * inv_fan; o.y = a1 * inv_fan; o.z = a2 * inv_fan; o.w = a3 * inv_fan;
    *(float4*)(A + t * 512 + lane * 4) = o;

    const long tl = tlid[t];
    *(float4*)(A + t * 512 + 256 + lane * 4) =
        *(const float4*)(X + tl * 256 + lane * 4);
}

// ---------------------------------------------------------------------------
// Kernel 2/4: fused (A @ [Wl;Wr] + b) -> LayerNorm -> ReLU.
// A: [M, 512] (agg | x_tgt), Wl/Wr: [256, 256] row-major (k-major), H: [M,256].
// Block = 256 threads (one per output column), BR rows per block.
// A elements are block-uniform -> scalar loads; W loads coalesced across j.
// ---------------------------------------------------------------------------
template <int BR>
__global__ __launch_bounds__(256) void sage_gemm_ln_relu(
    const float* __restrict__ A,
    const float* __restrict__ Wl, const float* __restrict__ Wr,
    const float* __restrict__ bias,
    const float* __restrict__ g, const float* __restrict__ be,
    float* __restrict__ H, int M)
{
    const int j = threadIdx.x;            // output column 0..255
    const long row0 = (long)blockIdx.x * BR;

    float acc[BR];
#pragma unroll
    for (int r = 0; r < BR; ++r) acc[r] = 0.f;

    const float* Ab = A + row0 * 512;

#pragma unroll 4
    for (int k = 0; k < 256; ++k) {
        const float wl = Wl[k * 256 + j];
        const float wr = Wr[k * 256 + j];
#pragma unroll
        for (int r = 0; r < BR; ++r) {
            acc[r] = fmaf(Ab[r * 512 + k],       wl, acc[r]);
            acc[r] = fmaf(Ab[r * 512 + 256 + k], wr, acc[r]);
        }
    }

    const float bj = bias[j];
#pragma unroll
    for (int r = 0; r < BR; ++r) acc[r] += bj;

    // LayerNorm across the 256 columns of each row: wave shuffle reduce, then
    // cross-wave combine via LDS (4 waves).
    __shared__ float partS[4][BR];
    __shared__ float partQ[4][BR];
    const int wave = j >> 6, lane = j & 63;

#pragma unroll
    for (int r = 0; r < BR; ++r) {
        float s = acc[r];
        float q = acc[r] * acc[r];
#pragma unroll
        for (int off = 32; off > 0; off >>= 1) {
            s += __shfl_down(s, off, 64);
            q += __shfl_down(q, off, 64);
        }
        if (lane == 0) { partS[wave][r] = s; partQ[wave][r] = q; }
    }
    __syncthreads();

    const float gj = g[j], bej = be[j];
#pragma unroll
    for (int r = 0; r < BR; ++r) {
        const float s = partS[0][r] + partS[1][r] + partS[2][r] + partS[3][r];
        const float q = partQ[0][r] + partQ[1][r] + partQ[2][r] + partQ[3][r];
        const float mu  = s * (1.f / 256.f);
        const float var = q * (1.f / 256.f) - mu * mu;
        const float hn  = (acc[r] - mu) * rsqrtf(var + LN_EPS) * gj + bej;
        H[(row0 + r) * 256 + j] = hn > 0.f ? hn : 0.f;
    }
}

// ---------------------------------------------------------------------------
// Kernel 5: final FC.  out[M, C] = H @ W + b.  W: [256, C] row-major.
// Thread per column (j < C), RB rows per block.
// ---------------------------------------------------------------------------
template <int RB>
__global__ __launch_bounds__(256) void fc_kernel(
    const float* __restrict__ Hh, const float* __restrict__ W,
    const float* __restrict__ bias, float* __restrict__ out,
    int M, int C)
{
    const int j = threadIdx.x;
    const long row0 = (long)blockIdx.x * RB;
    if (j >= C) return;

    float acc[RB];
    const float bj = bias[j];
#pragma unroll
    for (int r = 0; r < RB; ++r) acc[r] = bj;

    const float* Hb = Hh + row0 * 256;
#pragma unroll 4
    for (int k = 0; k < 256; ++k) {
        const float w = W[(long)k * C + j];
#pragma unroll
        for (int r = 0; r < RB; ++r)
            acc[r] = fmaf(Hb[r * 256 + k], w, acc[r]);
    }
#pragma unroll
    for (int r = 0; r < RB; ++r)
        out[(row0 + r) * C + j] = acc[r];
}

// ---------------------------------------------------------------------------
// Launch
// ---------------------------------------------------------------------------
extern "C" void kernel_launch(void* const* d_in, const int* in_sizes, int n_in,
                              void* d_out, int out_size, void* d_ws, size_t ws_size,
                              hipStream_t stream)
{
    const float* x_feat = (const float*)d_in[0];
    const int*   e0src  = (const int*)d_in[1];
    // d_in[2] = edge0_dst: structurally repeat(arange(N1), fan0) -> unused
    const int*   tlid0  = (const int*)d_in[3];
    const int*   e1src  = (const int*)d_in[4];
    // d_in[5] = edge1_dst: unused (same structure)
    const int*   tlid1  = (const int*)d_in[6];
    const float* Wl0 = (const float*)d_in[7];
    const float* Wr0 = (const float*)d_in[8];
    const float* b0  = (const float*)d_in[9];
    const float* g0  = (const float*)d_in[10];
    const float* be0 = (const float*)d_in[11];
    const float* Wl1 = (const float*)d_in[12];
    const float* Wr1 = (const float*)d_in[13];
    const float* b1  = (const float*)d_in[14];
    const float* g1  = (const float*)d_in[15];
    const float* be1 = (const float*)d_in[16];
    const float* fcW = (const float*)d_in[17];
    const float* fcb = (const float*)d_in[18];

    const int N1   = in_sizes[3];
    const int fan0 = in_sizes[1] / N1;
    const int N2   = in_sizes[6];
    const int fan1 = in_sizes[4] / N2;
    const int C    = in_sizes[18];

    // Workspace layout (bytes):
    //   A0: [N1,512] f32 at 0            (92.3 MB)  -- dead after layer-0 GEMM
    //   H0: [N1,256] f32 at N1*512*4     (46.1 MB)
    //   A1: [N2,512] f32 at 0            (reuses A0)
    //   H1: [N2,256] f32 at N2*512*4     (after A1, still inside old A0 region)
    float* A0 = (float*)d_ws;
    float* H0 = (float*)((char*)d_ws + (size_t)N1 * 512 * 4);
    float* A1 = (float*)d_ws;
    float* H1 = (float*)((char*)d_ws + (size_t)N2 * 512 * 4);

    // ---- Layer 0 ----
    gather_mean_kernel<<<(N1 + 3) / 4, 256, 0, stream>>>(
        x_feat, e0src, tlid0, A0, N1, fan0, 1.0f / (float)fan0);
    sage_gemm_ln_relu<32><<<(N1 + 31) / 32, 256, 0, stream>>>(
        A0, Wl0, Wr0, b0, g0, be0, H0, N1);

    // ---- Layer 1 ----
    gather_mean_kernel<<<(N2 + 3) / 4, 256, 0, stream>>>(
        H0, e1src, tlid1, A1, N2, fan1, 1.0f / (float)fan1);
    sage_gemm_ln_relu<32><<<(N2 + 31) / 32, 256, 0, stream>>>(
        A1, Wl1, Wr1, b1, g1, be1, H1, N2);

    // ---- FC ----
    fc_kernel<16><<<(N2 + 15) / 16, 256, 0, stream>>>(
        H1, fcW, fcb, (float*)d_out, N2, C);
}

// Round 2
// 248.321 us; speedup vs baseline: 4.2205x; 4.2205x over previous
//
#include <hip/hip_runtime.h>

#define LN_EPS 1e-5f

typedef __attribute__((ext_vector_type(4))) float f32x4;
typedef __attribute__((ext_vector_type(8))) short bf16x8;

__device__ inline float bf2f(ushort u) {
    union { unsigned u32; float f; } c; c.u32 = (unsigned)u << 16; return c.f;
}
__device__ inline ushort f2bf(float f) {
    union { float f; unsigned u; } c; c.f = f;
    unsigned r = c.u + 0x7FFF + ((c.u >> 16) & 1);   // round-to-nearest-even
    return (ushort)(r >> 16);
}

// ---------------------------------------------------------------------------
// Gather + mean aggregation -> bf16 A = [mean_agg (256) | x_tgt (256)].
// dst = repeat(arange(M), fan): target t owns edges [t*fan,(t+1)*fan), cnt==fan.
// One wave per target; lane owns 4 feature columns. FAN compile-time -> all
// row loads issued concurrently. T = float (layer 0) or ushort/bf16 (layer 1).
// ---------------------------------------------------------------------------
template <typename T, int FAN>
__global__ __launch_bounds__(256) void gather_mean_bf16(
    const T* __restrict__ X,         // [*, 256]
    const int* __restrict__ src,     // [M*fan]
    const int* __restrict__ tlid,    // [M]
    ushort* __restrict__ A,          // [M, 512] bf16
    int M, int fan_rt, float inv_fan)
{
    const int wave = threadIdx.x >> 6;
    const int lane = threadIdx.x & 63;
    const long t = (long)blockIdx.x * 4 + wave;
    if (t >= M) return;

    const int fan = FAN > 0 ? FAN : fan_rt;
    const int* es = src + t * (long)fan;
    float a0 = 0.f, a1 = 0.f, a2 = 0.f, a3 = 0.f;
#pragma unroll
    for (int e = 0; e < fan; ++e) {
        const long s = es[e];   // wave-uniform
        if constexpr (sizeof(T) == 4) {
            const float4 v = *(const float4*)((const float*)X + s * 256 + lane * 4);
            a0 += v.x; a1 += v.y; a2 += v.z; a3 += v.w;
        } else {
            const ushort4 v = *(const ushort4*)((const ushort*)X + s * 256 + lane * 4);
            a0 += bf2f(v.x); a1 += bf2f(v.y); a2 += bf2f(v.z); a3 += bf2f(v.w);
        }
    }
    ushort4 o;
    o.x = f2bf(a0 * inv_fan); o.y = f2bf(a1 * inv_fan);
    o.z = f2bf(a2 * inv_fan); o.w = f2bf(a3 * inv_fan);
    *(ushort4*)(A + t * 512 + lane * 4) = o;

    const long tl = tlid[t];
    ushort4 xt;
    if constexpr (sizeof(T) == 4) {
        const float4 v = *(const float4*)((const float*)X + tl * 256 + lane * 4);
        xt.x = f2bf(v.x); xt.y = f2bf(v.y); xt.z = f2bf(v.z); xt.w = f2bf(v.w);
    } else {
        xt = *(const ushort4*)((const ushort*)X + tl * 256 + lane * 4);
    }
    *(ushort4*)(A + t * 512 + 256 + lane * 4) = xt;
}

// ---------------------------------------------------------------------------
// Build Wt[256][512] bf16 with Wt[n][k] = (k<256 ? Wl[k][n] : Wr[k-256][n]).
// n-major so MFMA B-fragments are contiguous ds_read_b128.
// ---------------------------------------------------------------------------
__global__ __launch_bounds__(256) void convert_w(
    const float* __restrict__ Wl, const float* __restrict__ Wr,
    ushort* __restrict__ Wt)
{
    const int idx = blockIdx.x * 256 + threadIdx.x;   // 0 .. 256*512-1
    const int n = idx >> 9;
    const int k = idx & 511;
    const float v = (k < 256) ? Wl[k * 256 + n] : Wr[(k - 256) * 256 + n];
    Wt[idx] = f2bf(v);
}

// ---------------------------------------------------------------------------
// Fused MFMA GEMM + bias + LayerNorm + ReLU.
// A: [M,512] bf16. Wt: [256,512] bf16 (n-major). H: [M,256] bf16.
// Block: BM rows x 256 cols, 256 threads = 4 waves; wave w owns cols w*64..+64
// as (BM/16)x4 fragments of mfma_f32_16x16x32_bf16. BK=64 LDS staging, +8 pad.
// ---------------------------------------------------------------------------
template <int BM>
__global__ __launch_bounds__(256, 2) void sage_mfma_ln_relu(
    const ushort* __restrict__ A, const ushort* __restrict__ Wt,
    const float* __restrict__ bias, const float* __restrict__ g,
    const float* __restrict__ be, ushort* __restrict__ H, int M)
{
    constexpr int BK = 64, LDA = BK + 8;   // padded LDS stride (elements)
    constexpr int MI = BM / 16;
    __shared__ ushort As[BM * LDA];
    __shared__ ushort Ws[256 * LDA];
    __shared__ float rS[4][BM];
    __shared__ float rQ[4][BM];

    f32x4 acc[MI][4] = {};

    const int tid = threadIdx.x;
    const int wave = tid >> 6;
    const int lane = tid & 63;
    const int l15 = lane & 15;
    const int l4 = lane >> 4;
    const long row0 = (long)blockIdx.x * BM;
    const int col0 = wave * 64;

    for (int kc = 0; kc < 512; kc += BK) {
        // stage A-chunk: BM x 64 bf16, 16B segments
#pragma unroll
        for (int i = 0; i < BM / 32; ++i) {
            const int s = tid + i * 256;
            const int r = s >> 3, c = (s & 7) * 8;
            *(int4*)&As[r * LDA + c] = *(const int4*)&A[(row0 + r) * 512 + kc + c];
        }
        // stage Wt-chunk: 256 x 64 bf16
#pragma unroll
        for (int i = 0; i < 8; ++i) {
            const int s = tid + i * 256;
            const int r = s >> 3, c = (s & 7) * 8;
            *(int4*)&Ws[r * LDA + c] = *(const int4*)&Wt[r * 512 + kc + c];
        }
        __syncthreads();

#pragma unroll
        for (int ks = 0; ks < BK / 32; ++ks) {
            bf16x8 bfr[4], afr[MI];
#pragma unroll
            for (int ni = 0; ni < 4; ++ni)
                bfr[ni] = *(const bf16x8*)&Ws[(col0 + ni * 16 + l15) * LDA + ks * 32 + l4 * 8];
#pragma unroll
            for (int mi = 0; mi < MI; ++mi)
                afr[mi] = *(const bf16x8*)&As[(mi * 16 + l15) * LDA + ks * 32 + l4 * 8];
#pragma unroll
            for (int mi = 0; mi < MI; ++mi)
#pragma unroll
                for (int ni = 0; ni < 4; ++ni)
                    acc[mi][ni] = __builtin_amdgcn_mfma_f32_16x16x32_bf16(
                        afr[mi], bfr[ni], acc[mi][ni], 0, 0, 0);
        }
        __syncthreads();
    }

    // ---- epilogue: bias, LN stats, normalize, ReLU, bf16 store ----
    float bj[4], gj[4], bej[4];
#pragma unroll
    for (int ni = 0; ni < 4; ++ni) {
        const int c = col0 + ni * 16 + l15;
        bj[ni] = bias[c]; gj[ni] = g[c]; bej[ni] = be[c];
    }

#pragma unroll
    for (int mi = 0; mi < MI; ++mi) {
#pragma unroll
        for (int r = 0; r < 4; ++r) {
            float s = 0.f, q = 0.f;
#pragma unroll
            for (int ni = 0; ni < 4; ++ni) {
                const float v = acc[mi][ni][r] + bj[ni];
                acc[mi][ni][r] = v;
                s += v; q += v * v;
            }
#pragma unroll
            for (int off = 1; off < 16; off <<= 1) {
                s += __shfl_xor(s, off, 64);
                q += __shfl_xor(q, off, 64);
            }
            if (l15 == 0) {
                const int m = mi * 16 + l4 * 4 + r;
                rS[wave][m] = s; rQ[wave][m] = q;
            }
        }
    }
    __syncthreads();

#pragma unroll
    for (int mi = 0; mi < MI; ++mi) {
#pragma unroll
        for (int r = 0; r < 4; ++r) {
            const int m = mi * 16 + l4 * 4 + r;
            const float s = rS[0][m] + rS[1][m] + rS[2][m] + rS[3][m];
            const float q = rQ[0][m] + rQ[1][m] + rQ[2][m] + rQ[3][m];
            const float mu = s * (1.f / 256.f);
            const float var = q * (1.f / 256.f) - mu * mu;
            const float inv = rsqrtf(var + LN_EPS);
#pragma unroll
            for (int ni = 0; ni < 4; ++ni) {
                float hn = (acc[mi][ni][r] - mu) * inv * gj[ni] + bej[ni];
                hn = fmaxf(hn, 0.f);
                H[(row0 + m) * 256 + col0 + ni * 16 + l15] = f2bf(hn);
            }
        }
    }
}

// ---------------------------------------------------------------------------
// Final FC: out[M,C] = H @ W + b. H bf16, W/b/out f32. Thread per column.
// ---------------------------------------------------------------------------
template <int RB>
__global__ __launch_bounds__(256) void fc_kernel_bf(
    const ushort* __restrict__ Hh, const float* __restrict__ W,
    const float* __restrict__ bias, float* __restrict__ out,
    int M, int C)
{
    const int j = threadIdx.x;
    const long row0 = (long)blockIdx.x * RB;
    if (j >= C) return;

    float acc[RB];
    const float bjv = bias[j];
#pragma unroll
    for (int r = 0; r < RB; ++r) acc[r] = bjv;

    const ushort* Hb = Hh + row0 * 256;
#pragma unroll 4
    for (int k = 0; k < 256; ++k) {
        const float w = W[(long)k * C + j];
#pragma unroll
        for (int r = 0; r < RB; ++r)
            acc[r] = fmaf(bf2f(Hb[r * 256 + k]), w, acc[r]);
    }
#pragma unroll
    for (int r = 0; r < RB; ++r)
        out[(row0 + r) * C + j] = acc[r];
}

// ---------------------------------------------------------------------------
// Launch
// ---------------------------------------------------------------------------
extern "C" void kernel_launch(void* const* d_in, const int* in_sizes, int n_in,
                              void* d_out, int out_size, void* d_ws, size_t ws_size,
                              hipStream_t stream)
{
    const float* x_feat = (const float*)d_in[0];
    const int*   e0src  = (const int*)d_in[1];
    const int*   tlid0  = (const int*)d_in[3];
    const int*   e1src  = (const int*)d_in[4];
    const int*   tlid1  = (const int*)d_in[6];
    const float* Wl0 = (const float*)d_in[7];
    const float* Wr0 = (const float*)d_in[8];
    const float* b0  = (const float*)d_in[9];
    const float* g0  = (const float*)d_in[10];
    const float* be0 = (const float*)d_in[11];
    const float* Wl1 = (const float*)d_in[12];
    const float* Wr1 = (const float*)d_in[13];
    const float* b1  = (const float*)d_in[14];
    const float* g1  = (const float*)d_in[15];
    const float* be1 = (const float*)d_in[16];
    const float* fcW = (const float*)d_in[17];
    const float* fcb = (const float*)d_in[18];

    const int N1   = in_sizes[3];
    const int fan0 = in_sizes[1] / N1;
    const int N2   = in_sizes[6];
    const int fan1 = in_sizes[4] / N2;
    const int C    = in_sizes[18];

    // Workspace layout (bf16 elements unless noted):
    //   Wt0 [256][512]  (256 KB)
    //   Wt1 [256][512]  (256 KB)
    //   A0  [N1][512]   (46.1 MB)
    //   H0  [N1][256]   (23.1 MB)
    //   A1  [N2][512]   (4.2 MB)
    //   H1  [N2][256]   (2.1 MB)
    char* ws = (char*)d_ws;
    ushort* Wt0 = (ushort*)ws;                         ws += 256 * 512 * 2;
    ushort* Wt1 = (ushort*)ws;                         ws += 256 * 512 * 2;
    ushort* A0  = (ushort*)ws;                         ws += (size_t)N1 * 512 * 2;
    ushort* H0  = (ushort*)ws;                         ws += (size_t)N1 * 256 * 2;
    ushort* A1  = (ushort*)ws;                         ws += (size_t)N2 * 512 * 2;
    ushort* H1  = (ushort*)ws;

    convert_w<<<512, 256, 0, stream>>>(Wl0, Wr0, Wt0);
    convert_w<<<512, 256, 0, stream>>>(Wl1, Wr1, Wt1);

    // ---- Layer 0 ----
    if (fan0 == 15)
        gather_mean_bf16<float, 15><<<(N1 + 3) / 4, 256, 0, stream>>>(
            x_feat, e0src, tlid0, A0, N1, fan0, 1.0f / 15.0f);
    else
        gather_mean_bf16<float, 0><<<(N1 + 3) / 4, 256, 0, stream>>>(
            x_feat, e0src, tlid0, A0, N1, fan0, 1.0f / (float)fan0);
    sage_mfma_ln_relu<128><<<(N1 + 127) / 128, 256, 0, stream>>>(
        A0, Wt0, b0, g0, be0, H0, N1);

    // ---- Layer 1 ----
    if (fan1 == 10)
        gather_mean_bf16<ushort, 10><<<(N2 + 3) / 4, 256, 0, stream>>>(
            H0, e1src, tlid1, A1, N2, fan1, 1.0f / 10.0f);
    else
        gather_mean_bf16<ushort, 0><<<(N2 + 3) / 4, 256, 0, stream>>>(
            H0, e1src, tlid1, A1, N2, fan1, 1.0f / (float)fan1);
    sage_mfma_ln_relu<64><<<(N2 + 63) / 64, 256, 0, stream>>>(
        A1, Wt1, b1, g1, be1, H1, N2);

    // ---- FC ----
    fc_kernel_bf<16><<<(N2 + 15) / 16, 256, 0, stream>>>(
        H1, fcW, fcb, (float*)d_out, N2, C);
}

// Round 3
// 240.405 us; speedup vs baseline: 4.3594x; 1.0329x over previous
//
#include <hip/hip_runtime.h>

#define LN_EPS 1e-5f

typedef __attribute__((ext_vector_type(4))) float f32x4;
typedef __attribute__((ext_vector_type(8))) short bf16x8;

__device__ inline float bf2f(ushort u) {
    union { unsigned u32; float f; } c; c.u32 = (unsigned)u << 16; return c.f;
}
__device__ inline ushort f2bf(float f) {
    union { float f; unsigned u; } c; c.f = f;
    unsigned r = c.u + 0x7FFF + ((c.u >> 16) & 1);   // round-to-nearest-even
    return (ushort)(r >> 16);
}

// ---------------------------------------------------------------------------
// Gather + mean aggregation -> bf16 Aagg[M][256].
// dst = repeat(arange(M), fan): target t owns edges [t*fan,(t+1)*fan).
// One wave per target. Lane l<fan loads index l (one coalesced load per wave);
// row indices broadcast via shfl -> wave-uniform row loads, lane owns 4 cols.
// ---------------------------------------------------------------------------
template <typename T, int FAN>
__global__ __launch_bounds__(256, 4) void gather_mean_agg(
    const T* __restrict__ X,         // [*, 256]
    const int* __restrict__ src,     // [M*fan]
    ushort* __restrict__ A,          // [M, 256] bf16
    int M, int fan_rt, float inv_fan)
{
    const int wave = threadIdx.x >> 6;
    const int lane = threadIdx.x & 63;
    const long t = (long)blockIdx.x * 4 + wave;
    if (t >= M) return;

    const int fan = FAN > 0 ? FAN : fan_rt;
    int myidx = 0;
    if (lane < fan) myidx = src[t * (long)fan + lane];

    float a0 = 0.f, a1 = 0.f, a2 = 0.f, a3 = 0.f;

    auto body = [&](int e) {
        const long s = (long)__shfl(myidx, e, 64);
        if constexpr (sizeof(T) == 4) {
            const float4 v = *(const float4*)((const float*)X + s * 256 + lane * 4);
            a0 += v.x; a1 += v.y; a2 += v.z; a3 += v.w;
        } else {
            const ushort4 v = *(const ushort4*)((const ushort*)X + s * 256 + lane * 4);
            a0 += bf2f(v.x); a1 += bf2f(v.y); a2 += bf2f(v.z); a3 += bf2f(v.w);
        }
    };
    if constexpr (FAN > 0) {
#pragma unroll
        for (int e = 0; e < FAN; ++e) body(e);
    } else {
        for (int e = 0; e < fan; ++e) body(e);
    }

    ushort4 o;
    o.x = f2bf(a0 * inv_fan); o.y = f2bf(a1 * inv_fan);
    o.z = f2bf(a2 * inv_fan); o.w = f2bf(a3 * inv_fan);
    *(ushort4*)(A + t * 256 + lane * 4) = o;
}

// ---------------------------------------------------------------------------
// Build both Wt tensors in one launch.
// Wt[n][k] = (k<256 ? Wl[k][n] : Wr[k-256][n]), bf16, n-major [256][512].
// ---------------------------------------------------------------------------
__global__ __launch_bounds__(256) void convert_w2(
    const float* __restrict__ Wl0, const float* __restrict__ Wr0,
    const float* __restrict__ Wl1, const float* __restrict__ Wr1,
    ushort* __restrict__ Wt0, ushort* __restrict__ Wt1)
{
    const int idx = blockIdx.x * 256 + threadIdx.x;   // 0 .. 2*131072-1
    const int half = idx >> 17;
    const int local = idx & 131071;
    const int n = local >> 9;
    const int k = local & 511;
    const float* Wl = half ? Wl1 : Wl0;
    const float* Wr = half ? Wr1 : Wr0;
    const float v = (k < 256) ? Wl[k * 256 + n] : Wr[(k - 256) * 256 + n];
    (half ? Wt1 : Wt0)[local] = f2bf(v);
}

// ---------------------------------------------------------------------------
// Fused MFMA GEMM + bias + LayerNorm + ReLU.
// A-operand is [agg | x_tgt]: k<256 from Aagg[M][256] bf16; k>=256 gathered
// directly from Xsrc rows tlid[row] (f32 for layer 0, bf16 for layer 1).
// Wt: [256][512] bf16 n-major. H: [M,256] bf16.
// Block: BM rows x 256 cols, 4 waves; wave w owns cols w*64..+64 as
// (BM/16)x4 fragments of mfma_f32_16x16x32_bf16. BK=64 LDS staging, +8 pad.
// ---------------------------------------------------------------------------
template <int BM, typename XT>
__global__ __launch_bounds__(256, 2) void sage_mfma_ln_relu(
    const ushort* __restrict__ Aagg, const XT* __restrict__ Xsrc,
    const int* __restrict__ tlid, const ushort* __restrict__ Wt,
    const float* __restrict__ bias, const float* __restrict__ g,
    const float* __restrict__ be, ushort* __restrict__ H, int M)
{
    constexpr int BK = 64, LDA = BK + 8;   // padded LDS stride (elements)
    constexpr int MI = BM / 16;
    __shared__ ushort As[BM * LDA];
    __shared__ ushort Ws[256 * LDA];
    __shared__ float rS[4][BM];
    __shared__ float rQ[4][BM];
    __shared__ int tl[BM];

    f32x4 acc[MI][4] = {};

    const int tid = threadIdx.x;
    const int wave = tid >> 6;
    const int lane = tid & 63;
    const int l15 = lane & 15;
    const int l4 = lane >> 4;
    const long row0 = (long)blockIdx.x * BM;
    const int col0 = wave * 64;

    if (tid < BM) {
        long rr = row0 + tid; if (rr >= M) rr = M - 1;
        tl[tid] = tlid[rr];
    }
    // (visible at kc>=256 via the kc=0 __syncthreads)

    for (int kc = 0; kc < 512; kc += BK) {
        if (kc < 256) {
            // agg half: bf16 rows from Aagg
#pragma unroll
            for (int i = 0; i < BM / 32; ++i) {
                const int s = tid + i * 256;
                const int r = s >> 3, c = (s & 7) * 8;
                long rr = row0 + r; if (rr >= M) rr = M - 1;
                *(int4*)&As[r * LDA + c] = *(const int4*)&Aagg[rr * 256 + kc + c];
            }
        } else if constexpr (sizeof(XT) == 4) {
            // x_tgt half from f32 table, convert in-flight
#pragma unroll
            for (int i = 0; i < BM / 16; ++i) {
                const int s = tid + i * 256;
                const int r = s >> 4, c4 = (s & 15) * 4;
                const float4 v = *(const float4*)&(
                    (const float*)Xsrc)[(long)tl[r] * 256 + (kc - 256) + c4];
                ushort4 o;
                o.x = f2bf(v.x); o.y = f2bf(v.y); o.z = f2bf(v.z); o.w = f2bf(v.w);
                *(ushort4*)&As[r * LDA + c4] = o;
            }
        } else {
            // x_tgt half from bf16 table
#pragma unroll
            for (int i = 0; i < BM / 32; ++i) {
                const int s = tid + i * 256;
                const int r = s >> 3, c = (s & 7) * 8;
                *(int4*)&As[r * LDA + c] = *(const int4*)&(
                    (const ushort*)Xsrc)[(long)tl[r] * 256 + (kc - 256) + c];
            }
        }
        // stage Wt-chunk: 256 x 64 bf16
#pragma unroll
        for (int i = 0; i < 8; ++i) {
            const int s = tid + i * 256;
            const int r = s >> 3, c = (s & 7) * 8;
            *(int4*)&Ws[r * LDA + c] = *(const int4*)&Wt[r * 512 + kc + c];
        }
        __syncthreads();

#pragma unroll
        for (int ks = 0; ks < BK / 32; ++ks) {
            bf16x8 bfr[4], afr[MI];
#pragma unroll
            for (int ni = 0; ni < 4; ++ni)
                bfr[ni] = *(const bf16x8*)&Ws[(col0 + ni * 16 + l15) * LDA + ks * 32 + l4 * 8];
#pragma unroll
            for (int mi = 0; mi < MI; ++mi)
                afr[mi] = *(const bf16x8*)&As[(mi * 16 + l15) * LDA + ks * 32 + l4 * 8];
#pragma unroll
            for (int mi = 0; mi < MI; ++mi)
#pragma unroll
                for (int ni = 0; ni < 4; ++ni)
                    acc[mi][ni] = __builtin_amdgcn_mfma_f32_16x16x32_bf16(
                        afr[mi], bfr[ni], acc[mi][ni], 0, 0, 0);
        }
        __syncthreads();
    }

    // ---- epilogue: bias, LN stats, normalize, ReLU, bf16 store ----
    float bj[4], gj[4], bej[4];
#pragma unroll
    for (int ni = 0; ni < 4; ++ni) {
        const int c = col0 + ni * 16 + l15;
        bj[ni] = bias[c]; gj[ni] = g[c]; bej[ni] = be[c];
    }

#pragma unroll
    for (int mi = 0; mi < MI; ++mi) {
#pragma unroll
        for (int r = 0; r < 4; ++r) {
            float s = 0.f, q = 0.f;
#pragma unroll
            for (int ni = 0; ni < 4; ++ni) {
                const float v = acc[mi][ni][r] + bj[ni];
                acc[mi][ni][r] = v;
                s += v; q += v * v;
            }
#pragma unroll
            for (int off = 1; off < 16; off <<= 1) {
                s += __shfl_xor(s, off, 64);
                q += __shfl_xor(q, off, 64);
            }
            if (l15 == 0) {
                const int m = mi * 16 + l4 * 4 + r;
                rS[wave][m] = s; rQ[wave][m] = q;
            }
        }
    }
    __syncthreads();

#pragma unroll
    for (int mi = 0; mi < MI; ++mi) {
#pragma unroll
        for (int r = 0; r < 4; ++r) {
            const int m = mi * 16 + l4 * 4 + r;
            if (row0 + m >= M) continue;
            const float s = rS[0][m] + rS[1][m] + rS[2][m] + rS[3][m];
            const float q = rQ[0][m] + rQ[1][m] + rQ[2][m] + rQ[3][m];
            const float mu = s * (1.f / 256.f);
            const float var = q * (1.f / 256.f) - mu * mu;
            const float inv = rsqrtf(var + LN_EPS);
#pragma unroll
            for (int ni = 0; ni < 4; ++ni) {
                float hn = (acc[mi][ni][r] - mu) * inv * gj[ni] + bej[ni];
                hn = fmaxf(hn, 0.f);
                H[(row0 + m) * 256 + col0 + ni * 16 + l15] = f2bf(hn);
            }
        }
    }
}

// ---------------------------------------------------------------------------
// Final FC: out[M,C] = H @ W + b. H bf16, W/b/out f32. Thread per column.
// ---------------------------------------------------------------------------
template <int RB>
__global__ __launch_bounds__(256) void fc_kernel_bf(
    const ushort* __restrict__ Hh, const float* __restrict__ W,
    const float* __restrict__ bias, float* __restrict__ out,
    int M, int C)
{
    const int j = threadIdx.x;
    const long row0 = (long)blockIdx.x * RB;
    if (j >= C) return;

    float acc[RB];
    const float bjv = bias[j];
#pragma unroll
    for (int r = 0; r < RB; ++r) acc[r] = bjv;

    const ushort* Hb = Hh + row0 * 256;
#pragma unroll 4
    for (int k = 0; k < 256; ++k) {
        const float w = W[(long)k * C + j];
#pragma unroll
        for (int r = 0; r < RB; ++r)
            acc[r] = fmaf(bf2f(Hb[r * 256 + k]), w, acc[r]);
    }
#pragma unroll
    for (int r = 0; r < RB; ++r)
        if (row0 + r < M) out[(row0 + r) * C + j] = acc[r];
}

// ---------------------------------------------------------------------------
// Launch
// ---------------------------------------------------------------------------
extern "C" void kernel_launch(void* const* d_in, const int* in_sizes, int n_in,
                              void* d_out, int out_size, void* d_ws, size_t ws_size,
                              hipStream_t stream)
{
    const float* x_feat = (const float*)d_in[0];
    const int*   e0src  = (const int*)d_in[1];
    const int*   tlid0  = (const int*)d_in[3];
    const int*   e1src  = (const int*)d_in[4];
    const int*   tlid1  = (const int*)d_in[6];
    const float* Wl0 = (const float*)d_in[7];
    const float* Wr0 = (const float*)d_in[8];
    const float* b0  = (const float*)d_in[9];
    const float* g0  = (const float*)d_in[10];
    const float* be0 = (const float*)d_in[11];
    const float* Wl1 = (const float*)d_in[12];
    const float* Wr1 = (const float*)d_in[13];
    const float* b1  = (const float*)d_in[14];
    const float* g1  = (const float*)d_in[15];
    const float* be1 = (const float*)d_in[16];
    const float* fcW = (const float*)d_in[17];
    const float* fcb = (const float*)d_in[18];

    const int N1   = in_sizes[3];
    const int fan0 = in_sizes[1] / N1;
    const int N2   = in_sizes[6];
    const int fan1 = in_sizes[4] / N2;
    const int C    = in_sizes[18];

    // Workspace (bf16 unless noted):
    //   Wt0 [256][512], Wt1 [256][512]  (256 KB each)
    //   A0  [N1][256]  (23.1 MB)   H0 [N1][256]  (23.1 MB)
    //   A1  [N2][256]  (2.1 MB)    H1 [N2][256]  (2.1 MB)
    char* ws = (char*)d_ws;
    ushort* Wt0 = (ushort*)ws;                         ws += 256 * 512 * 2;
    ushort* Wt1 = (ushort*)ws;                         ws += 256 * 512 * 2;
    ushort* A0  = (ushort*)ws;                         ws += (size_t)N1 * 256 * 2;
    ushort* H0  = (ushort*)ws;                         ws += (size_t)N1 * 256 * 2;
    ushort* A1  = (ushort*)ws;                         ws += (size_t)N2 * 256 * 2;
    ushort* H1  = (ushort*)ws;

    convert_w2<<<1024, 256, 0, stream>>>(Wl0, Wr0, Wl1, Wr1, Wt0, Wt1);

    // ---- Layer 0 ----
    if (fan0 == 15)
        gather_mean_agg<float, 15><<<(N1 + 3) / 4, 256, 0, stream>>>(
            x_feat, e0src, A0, N1, fan0, 1.0f / 15.0f);
    else
        gather_mean_agg<float, 0><<<(N1 + 3) / 4, 256, 0, stream>>>(
            x_feat, e0src, A0, N1, fan0, 1.0f / (float)fan0);
    sage_mfma_ln_relu<128, float><<<(N1 + 127) / 128, 256, 0, stream>>>(
        A0, x_feat, tlid0, Wt0, b0, g0, be0, H0, N1);

    // ---- Layer 1 ----
    if (fan1 == 10)
        gather_mean_agg<ushort, 10><<<(N2 + 3) / 4, 256, 0, stream>>>(
            H0, e1src, A1, N2, fan1, 1.0f / 10.0f);
    else
        gather_mean_agg<ushort, 0><<<(N2 + 3) / 4, 256, 0, stream>>>(
            H0, e1src, A1, N2, fan1, 1.0f / (float)fan1);
    sage_mfma_ln_relu<64, ushort><<<(N2 + 63) / 64, 256, 0, stream>>>(
        A1, H0, tlid1, Wt1, b1, g1, be1, H1, N2);

    // ---- FC ----
    fc_kernel_bf<16><<<(N2 + 15) / 16, 256, 0, stream>>>(
        H1, fcW, fcb, (float*)d_out, N2, C);
}

// Round 4
// 236.395 us; speedup vs baseline: 4.4334x; 1.0170x over previous
//
#include <hip/hip_runtime.h>

#define LN_EPS 1e-5f

typedef __attribute__((ext_vector_type(4))) float f32x4;
typedef __attribute__((ext_vector_type(8))) short bf16x8;

__device__ inline float bf2f(ushort u) {
    union { unsigned u32; float f; } c; c.u32 = (unsigned)u << 16; return c.f;
}
__device__ inline ushort f2bf(float f) {
    union { float f; unsigned u; } c; c.f = f;
    unsigned r = c.u + 0x7FFF + ((c.u >> 16) & 1);   // round-to-nearest-even
    return (ushort)(r >> 16);
}

// async global->LDS, 16B per lane. LDS operand must be the WAVE-UNIFORM base;
// HW adds lane*16. Global operand is per-lane.
__device__ inline void gload16(const void* gsrc, void* lds_base_uniform) {
    __builtin_amdgcn_global_load_lds(
        (const __attribute__((address_space(1))) unsigned*)gsrc,
        (__attribute__((address_space(3))) unsigned*)lds_base_uniform, 16, 0, 0);
}

// ---------------------------------------------------------------------------
// Gather + mean aggregation -> bf16 Aagg[M][256].
// SWZ: store each row content-pre-swizzled per 64-col group:
//   elem index = (c&~63) | ((c&63) ^ ((t&7)<<3))
// so that gemm0's linear global_load_lds lands the XOR-swizzled LDS image.
// ---------------------------------------------------------------------------
template <typename T, int FAN, bool SWZ>
__global__ __launch_bounds__(256, 4) void gather_mean_agg(
    const T* __restrict__ X,         // [*, 256]
    const int* __restrict__ src,     // [M*fan]
    ushort* __restrict__ A,          // [M, 256] bf16
    int M, int fan_rt, float inv_fan)
{
    const int wave = threadIdx.x >> 6;
    const int lane = threadIdx.x & 63;
    const long t = (long)blockIdx.x * 4 + wave;
    if (t >= M) return;

    const int fan = FAN > 0 ? FAN : fan_rt;
    int myidx = 0;
    if (lane < fan) myidx = src[t * (long)fan + lane];

    float a0 = 0.f, a1 = 0.f, a2 = 0.f, a3 = 0.f;

    auto body = [&](int e) {
        const long s = (long)__shfl(myidx, e, 64);
        if constexpr (sizeof(T) == 4) {
            const float4 v = *(const float4*)((const float*)X + s * 256 + lane * 4);
            a0 += v.x; a1 += v.y; a2 += v.z; a3 += v.w;
        } else {
            const ushort4 v = *(const ushort4*)((const ushort*)X + s * 256 + lane * 4);
            a0 += bf2f(v.x); a1 += bf2f(v.y); a2 += bf2f(v.z); a3 += bf2f(v.w);
        }
    };
    if constexpr (FAN > 0) {
#pragma unroll
        for (int e = 0; e < FAN; ++e) body(e);
    } else {
        for (int e = 0; e < fan; ++e) body(e);
    }

    ushort4 o;
    o.x = f2bf(a0 * inv_fan); o.y = f2bf(a1 * inv_fan);
    o.z = f2bf(a2 * inv_fan); o.w = f2bf(a3 * inv_fan);

    if constexpr (SWZ) {
        const int c = lane * 4;
        const int idx = (c & ~63) | ((c & 63) ^ (((int)t & 7) << 3));
        *(ushort4*)(A + t * 256 + idx) = o;
    } else {
        *(ushort4*)(A + t * 256 + lane * 4) = o;
    }
}

// ---------------------------------------------------------------------------
// Wt0: swizzled chunk-major [8 chunks][16384 elems]; within chunk:
//   elem e holds logical (n = e>>6, k = chunk*64 + ((e&63) ^ ((n&7)<<3)))
// Wt1: plain n-major [256][512].
// logical(n,k) = k<256 ? Wl[k][n] : Wr[k-256][n].
// ---------------------------------------------------------------------------
__global__ __launch_bounds__(256) void convert_w2(
    const float* __restrict__ Wl0, const float* __restrict__ Wr0,
    const float* __restrict__ Wl1, const float* __restrict__ Wr1,
    ushort* __restrict__ Wt0, ushort* __restrict__ Wt1)
{
    const int idx = blockIdx.x * 256 + threadIdx.x;   // 0 .. 262143
    const int half = idx >> 17;
    const int local = idx & 131071;
    if (half == 0) {
        const int chunk = local >> 14;
        const int e = local & 16383;
        const int n = e >> 6;
        const int kl = (e & 63) ^ ((n & 7) << 3);
        const int k = chunk * 64 + kl;
        const float v = (k < 256) ? Wl0[k * 256 + n] : Wr0[(k - 256) * 256 + n];
        Wt0[local] = f2bf(v);
    } else {
        const int n = local >> 9;
        const int k = local & 511;
        const float v = (k < 256) ? Wl1[k * 256 + n] : Wr1[(k - 256) * 256 + n];
        Wt1[local] = f2bf(v);
    }
}

// ---------------------------------------------------------------------------
// Layer-0 fused MFMA GEMM + bias + LayerNorm + ReLU, global_load_lds staging.
// A0: [M][256] bf16 content-swizzled rows (k<256 half).
// Xsrc: f32 table, rows tlid[row] = x_tgt (k>=256 half), manual swizzled stage.
// Wt: [8][16384] bf16 swizzled chunk-major.
// LDS images are [rows][64] bf16 linear; fragment reads XOR ((row&7)<<4).
// ---------------------------------------------------------------------------
__global__ __launch_bounds__(256, 2) void sage_mfma_swz(
    const ushort* __restrict__ A0, const float* __restrict__ Xsrc,
    const int* __restrict__ tlid, const ushort* __restrict__ Wt,
    const float* __restrict__ bias, const float* __restrict__ g,
    const float* __restrict__ be, ushort* __restrict__ H, int M)
{
    constexpr int BM = 128, MI = 8;
    __shared__ ushort As[BM * 64];    // 16 KB swizzled image of current chunk
    __shared__ ushort Ws[256 * 64];   // 32 KB swizzled image of current chunk
    __shared__ float rS[4][BM];
    __shared__ float rQ[4][BM];
    __shared__ int tl[BM];

    f32x4 acc[MI][4] = {};

    const int tid = threadIdx.x;
    const int wave = tid >> 6;
    const int lane = tid & 63;
    const int l15 = lane & 15;
    const int l4 = lane >> 4;
    const long row0 = (long)blockIdx.x * BM;
    const int col0 = wave * 64;

    if (tid < BM) {
        long rr = row0 + tid; if (rr >= M) rr = M - 1;
        tl[tid] = tlid[rr];
    }
    // visible by kc8==4 via earlier __syncthreads

    for (int kc8 = 0; kc8 < 8; ++kc8) {
        const int kc = kc8 * 64;
        if (kc8 < 4) {
            // As via global_load_lds: per wave 4 x 1KB; A0 content pre-swizzled.
#pragma unroll
            for (int i = 0; i < 4; ++i) {
                const int base = wave * 4096 + i * 1024;      // uniform
                const int off = base + lane * 16;             // per-lane
                const int r = off >> 7;
                gload16((const char*)A0 + (size_t)(row0 + r) * 512 + kc * 2 + (off & 127),
                        (char*)As + base);
            }
        } else {
            // x_tgt half: f32 gather + convert, manual swizzled ds_write.
#pragma unroll
            for (int it = 0; it < 8; ++it) {
                const int s = tid + it * 256;   // 0..2047
                const int r = s >> 4;            // row 0..127
                const int c = (s & 15) * 4;      // col-in-chunk 0..60
                const float4 v = *(const float4*)&Xsrc[(size_t)tl[r] * 256 + (kc - 256) + c];
                ushort4 o;
                o.x = f2bf(v.x); o.y = f2bf(v.y); o.z = f2bf(v.z); o.w = f2bf(v.w);
                const int byte = (r * 128 + c * 2) ^ ((r & 7) << 4);
                *(ushort4*)((char*)As + byte) = o;
            }
        }
        // Ws via global_load_lds: per wave 8 x 1KB; Wt content pre-swizzled.
#pragma unroll
        for (int i = 0; i < 8; ++i) {
            const int base = wave * 8192 + i * 1024;
            const int off = base + lane * 16;
            gload16((const char*)Wt + kc8 * 32768 + off, (char*)Ws + base);
        }
        __syncthreads();

#pragma unroll
        for (int ks = 0; ks < 2; ++ks) {
            bf16x8 bfr[4], afr[MI];
#pragma unroll
            for (int ni = 0; ni < 4; ++ni) {
                const int n = col0 + ni * 16 + l15;
                const int byte = (n * 128 + ks * 64 + l4 * 16) ^ ((n & 7) << 4);
                bfr[ni] = *(const bf16x8*)((const char*)Ws + byte);
            }
#pragma unroll
            for (int mi = 0; mi < MI; ++mi) {
                const int r = mi * 16 + l15;
                const int byte = (r * 128 + ks * 64 + l4 * 16) ^ ((r & 7) << 4);
                afr[mi] = *(const bf16x8*)((const char*)As + byte);
            }
#pragma unroll
            for (int mi = 0; mi < MI; ++mi)
#pragma unroll
                for (int ni = 0; ni < 4; ++ni)
                    acc[mi][ni] = __builtin_amdgcn_mfma_f32_16x16x32_bf16(
                        afr[mi], bfr[ni], acc[mi][ni], 0, 0, 0);
        }
        __syncthreads();
    }

    // ---- epilogue: bias, LN stats, normalize, ReLU, bf16 store ----
    float bj[4], gj[4], bej[4];
#pragma unroll
    for (int ni = 0; ni < 4; ++ni) {
        const int c = col0 + ni * 16 + l15;
        bj[ni] = bias[c]; gj[ni] = g[c]; bej[ni] = be[c];
    }

#pragma unroll
    for (int mi = 0; mi < MI; ++mi) {
#pragma unroll
        for (int r = 0; r < 4; ++r) {
            float s = 0.f, q = 0.f;
#pragma unroll
            for (int ni = 0; ni < 4; ++ni) {
                const float v = acc[mi][ni][r] + bj[ni];
                acc[mi][ni][r] = v;
                s += v; q += v * v;
            }
#pragma unroll
            for (int off = 1; off < 16; off <<= 1) {
                s += __shfl_xor(s, off, 64);
                q += __shfl_xor(q, off, 64);
            }
            if (l15 == 0) {
                const int m = mi * 16 + l4 * 4 + r;
                rS[wave][m] = s; rQ[wave][m] = q;
            }
        }
    }
    __syncthreads();

#pragma unroll
    for (int mi = 0; mi < MI; ++mi) {
#pragma unroll
        for (int r = 0; r < 4; ++r) {
            const int m = mi * 16 + l4 * 4 + r;
            if (row0 + m >= M) continue;
            const float s = rS[0][m] + rS[1][m] + rS[2][m] + rS[3][m];
            const float q = rQ[0][m] + rQ[1][m] + rQ[2][m] + rQ[3][m];
            const float mu = s * (1.f / 256.f);
            const float var = q * (1.f / 256.f) - mu * mu;
            const float inv = rsqrtf(var + LN_EPS);
#pragma unroll
            for (int ni = 0; ni < 4; ++ni) {
                float hn = (acc[mi][ni][r] - mu) * inv * gj[ni] + bej[ni];
                hn = fmaxf(hn, 0.f);
                H[(row0 + m) * 256 + col0 + ni * 16 + l15] = f2bf(hn);
            }
        }
    }
}

// ---------------------------------------------------------------------------
// Layer-1 MFMA GEMM (unchanged round-3 path, padded-LDS manual staging).
// ---------------------------------------------------------------------------
template <int BM, typename XT>
__global__ __launch_bounds__(256, 2) void sage_mfma_ln_relu(
    const ushort* __restrict__ Aagg, const XT* __restrict__ Xsrc,
    const int* __restrict__ tlid, const ushort* __restrict__ Wt,
    const float* __restrict__ bias, const float* __restrict__ g,
    const float* __restrict__ be, ushort* __restrict__ H, int M)
{
    constexpr int BK = 64, LDA = BK + 8;
    constexpr int MI = BM / 16;
    __shared__ ushort As[BM * LDA];
    __shared__ ushort Ws[256 * LDA];
    __shared__ float rS[4][BM];
    __shared__ float rQ[4][BM];
    __shared__ int tl[BM];

    f32x4 acc[MI][4] = {};

    const int tid = threadIdx.x;
    const int wave = tid >> 6;
    const int lane = tid & 63;
    const int l15 = lane & 15;
    const int l4 = lane >> 4;
    const long row0 = (long)blockIdx.x * BM;
    const int col0 = wave * 64;

    if (tid < BM) {
        long rr = row0 + tid; if (rr >= M) rr = M - 1;
        tl[tid] = tlid[rr];
    }

    for (int kc = 0; kc < 512; kc += BK) {
        if (kc < 256) {
#pragma unroll
            for (int i = 0; i < BM / 32; ++i) {
                const int s = tid + i * 256;
                const int r = s >> 3, c = (s & 7) * 8;
                long rr = row0 + r; if (rr >= M) rr = M - 1;
                *(int4*)&As[r * LDA + c] = *(const int4*)&Aagg[rr * 256 + kc + c];
            }
        } else {
#pragma unroll
            for (int i = 0; i < BM / 32; ++i) {
                const int s = tid + i * 256;
                const int r = s >> 3, c = (s & 7) * 8;
                *(int4*)&As[r * LDA + c] = *(const int4*)&(
                    (const ushort*)Xsrc)[(long)tl[r] * 256 + (kc - 256) + c];
            }
        }
#pragma unroll
        for (int i = 0; i < 8; ++i) {
            const int s = tid + i * 256;
            const int r = s >> 3, c = (s & 7) * 8;
            *(int4*)&Ws[r * LDA + c] = *(const int4*)&Wt[r * 512 + kc + c];
        }
        __syncthreads();

#pragma unroll
        for (int ks = 0; ks < BK / 32; ++ks) {
            bf16x8 bfr[4], afr[MI];
#pragma unroll
            for (int ni = 0; ni < 4; ++ni)
                bfr[ni] = *(const bf16x8*)&Ws[(col0 + ni * 16 + l15) * LDA + ks * 32 + l4 * 8];
#pragma unroll
            for (int mi = 0; mi < MI; ++mi)
                afr[mi] = *(const bf16x8*)&As[(mi * 16 + l15) * LDA + ks * 32 + l4 * 8];
#pragma unroll
            for (int mi = 0; mi < MI; ++mi)
#pragma unroll
                for (int ni = 0; ni < 4; ++ni)
                    acc[mi][ni] = __builtin_amdgcn_mfma_f32_16x16x32_bf16(
                        afr[mi], bfr[ni], acc[mi][ni], 0, 0, 0);
        }
        __syncthreads();
    }

    float bj[4], gj[4], bej[4];
#pragma unroll
    for (int ni = 0; ni < 4; ++ni) {
        const int c = col0 + ni * 16 + l15;
        bj[ni] = bias[c]; gj[ni] = g[c]; bej[ni] = be[c];
    }

#pragma unroll
    for (int mi = 0; mi < MI; ++mi) {
#pragma unroll
        for (int r = 0; r < 4; ++r) {
            float s = 0.f, q = 0.f;
#pragma unroll
            for (int ni = 0; ni < 4; ++ni) {
                const float v = acc[mi][ni][r] + bj[ni];
                acc[mi][ni][r] = v;
                s += v; q += v * v;
            }
#pragma unroll
            for (int off = 1; off < 16; off <<= 1) {
                s += __shfl_xor(s, off, 64);
                q += __shfl_xor(q, off, 64);
            }
            if (l15 == 0) {
                const int m = mi * 16 + l4 * 4 + r;
                rS[wave][m] = s; rQ[wave][m] = q;
            }
        }
    }
    __syncthreads();

#pragma unroll
    for (int mi = 0; mi < MI; ++mi) {
#pragma unroll
        for (int r = 0; r < 4; ++r) {
            const int m = mi * 16 + l4 * 4 + r;
            if (row0 + m >= M) continue;
            const float s = rS[0][m] + rS[1][m] + rS[2][m] + rS[3][m];
            const float q = rQ[0][m] + rQ[1][m] + rQ[2][m] + rQ[3][m];
            const float mu = s * (1.f / 256.f);
            const float var = q * (1.f / 256.f) - mu * mu;
            const float inv = rsqrtf(var + LN_EPS);
#pragma unroll
            for (int ni = 0; ni < 4; ++ni) {
                float hn = (acc[mi][ni][r] - mu) * inv * gj[ni] + bej[ni];
                hn = fmaxf(hn, 0.f);
                H[(row0 + m) * 256 + col0 + ni * 16 + l15] = f2bf(hn);
            }
        }
    }
}

// ---------------------------------------------------------------------------
// Final FC: out[M,C] = H @ W + b. H bf16, W/b/out f32.
// ---------------------------------------------------------------------------
template <int RB>
__global__ __launch_bounds__(256) void fc_kernel_bf(
    const ushort* __restrict__ Hh, const float* __restrict__ W,
    const float* __restrict__ bias, float* __restrict__ out,
    int M, int C)
{
    const int j = threadIdx.x;
    const long row0 = (long)blockIdx.x * RB;
    if (j >= C) return;

    float acc[RB];
    const float bjv = bias[j];
#pragma unroll
    for (int r = 0; r < RB; ++r) acc[r] = bjv;

    const ushort* Hb = Hh + row0 * 256;
#pragma unroll 4
    for (int k = 0; k < 256; ++k) {
        const float w = W[(long)k * C + j];
#pragma unroll
        for (int r = 0; r < RB; ++r)
            acc[r] = fmaf(bf2f(Hb[r * 256 + k]), w, acc[r]);
    }
#pragma unroll
    for (int r = 0; r < RB; ++r)
        if (row0 + r < M) out[(row0 + r) * C + j] = acc[r];
}

// ---------------------------------------------------------------------------
// Launch
// ---------------------------------------------------------------------------
extern "C" void kernel_launch(void* const* d_in, const int* in_sizes, int n_in,
                              void* d_out, int out_size, void* d_ws, size_t ws_size,
                              hipStream_t stream)
{
    const float* x_feat = (const float*)d_in[0];
    const int*   e0src  = (const int*)d_in[1];
    const int*   tlid0  = (const int*)d_in[3];
    const int*   e1src  = (const int*)d_in[4];
    const int*   tlid1  = (const int*)d_in[6];
    const float* Wl0 = (const float*)d_in[7];
    const float* Wr0 = (const float*)d_in[8];
    const float* b0  = (const float*)d_in[9];
    const float* g0  = (const float*)d_in[10];
    const float* be0 = (const float*)d_in[11];
    const float* Wl1 = (const float*)d_in[12];
    const float* Wr1 = (const float*)d_in[13];
    const float* b1  = (const float*)d_in[14];
    const float* g1  = (const float*)d_in[15];
    const float* be1 = (const float*)d_in[16];
    const float* fcW = (const float*)d_in[17];
    const float* fcb = (const float*)d_in[18];

    const int N1   = in_sizes[3];
    const int fan0 = in_sizes[1] / N1;
    const int N2   = in_sizes[6];
    const int fan1 = in_sizes[4] / N2;
    const int C    = in_sizes[18];

    // Workspace:
    //   Wt0 [8][16384] bf16 (swizzled chunk-major), Wt1 [256][512] bf16
    //   A0 [N1][256] bf16 (content-swizzled rows), H0 [N1][256] bf16
    //   A1 [N2][256] bf16 (plain), H1 [N2][256] bf16
    char* ws = (char*)d_ws;
    ushort* Wt0 = (ushort*)ws;                         ws += 256 * 512 * 2;
    ushort* Wt1 = (ushort*)ws;                         ws += 256 * 512 * 2;
    ushort* A0  = (ushort*)ws;                         ws += (size_t)N1 * 256 * 2;
    ushort* H0  = (ushort*)ws;                         ws += (size_t)N1 * 256 * 2;
    ushort* A1  = (ushort*)ws;                         ws += (size_t)N2 * 256 * 2;
    ushort* H1  = (ushort*)ws;

    convert_w2<<<1024, 256, 0, stream>>>(Wl0, Wr0, Wl1, Wr1, Wt0, Wt1);

    // ---- Layer 0 ----
    if (fan0 == 15)
        gather_mean_agg<float, 15, true><<<(N1 + 3) / 4, 256, 0, stream>>>(
            x_feat, e0src, A0, N1, fan0, 1.0f / 15.0f);
    else
        gather_mean_agg<float, 0, true><<<(N1 + 3) / 4, 256, 0, stream>>>(
            x_feat, e0src, A0, N1, fan0, 1.0f / (float)fan0);
    sage_mfma_swz<<<(N1 + 127) / 128, 256, 0, stream>>>(
        A0, x_feat, tlid0, Wt0, b0, g0, be0, H0, N1);

    // ---- Layer 1 (round-3 path, unchanged) ----
    if (fan1 == 10)
        gather_mean_agg<ushort, 10, false><<<(N2 + 3) / 4, 256, 0, stream>>>(
            H0, e1src, A1, N2, fan1, 1.0f / 10.0f);
    else
        gather_mean_agg<ushort, 0, false><<<(N2 + 3) / 4, 256, 0, stream>>>(
            H0, e1src, A1, N2, fan1, 1.0f / (float)fan1);
    sage_mfma_ln_relu<64, ushort><<<(N2 + 63) / 64, 256, 0, stream>>>(
        A1, H0, tlid1, Wt1, b1, g1, be1, H1, N2);

    // ---- FC ----
    fc_kernel_bf<16><<<(N2 + 15) / 16, 256, 0, stream>>>(
        H1, fcW, fcb, (float*)d_out, N2, C);
}

// Round 5
// 235.539 us; speedup vs baseline: 4.4495x; 1.0036x over previous
//
#include <hip/hip_runtime.h>

#define LN_EPS 1e-5f

typedef __attribute__((ext_vector_type(4))) float f32x4;
typedef __attribute__((ext_vector_type(8))) short bf16x8;

__device__ inline float bf2f(ushort u) {
    union { unsigned u32; float f; } c; c.u32 = (unsigned)u << 16; return c.f;
}
__device__ inline ushort f2bf(float f) {
    union { float f; unsigned u; } c; c.f = f;
    unsigned r = c.u + 0x7FFF + ((c.u >> 16) & 1);   // round-to-nearest-even
    return (ushort)(r >> 16);
}

// async global->LDS, 16B per lane. LDS operand is the WAVE-UNIFORM base
// (HW adds lane*16); global operand is per-lane.
__device__ inline void gload16(const void* gsrc, void* lds_base_uniform) {
    __builtin_amdgcn_global_load_lds(
        (const __attribute__((address_space(1))) unsigned*)gsrc,
        (__attribute__((address_space(3))) unsigned*)lds_base_uniform, 16, 0, 0);
}

// ---------------------------------------------------------------------------
// Both Wt tensors, swizzled chunk-major [8 chunks][16384 elems]; within chunk:
//   elem e holds logical (n = e>>6, k = chunk*64 + ((e&63) ^ ((n&7)<<3)))
// logical(n,k) = k<256 ? Wl[k][n] : Wr[k-256][n].
// ---------------------------------------------------------------------------
__global__ __launch_bounds__(256) void convert_w2(
    const float* __restrict__ Wl0, const float* __restrict__ Wr0,
    const float* __restrict__ Wl1, const float* __restrict__ Wr1,
    ushort* __restrict__ Wt0, ushort* __restrict__ Wt1)
{
    const int idx = blockIdx.x * 256 + threadIdx.x;   // 0 .. 262143
    const int half = idx >> 17;
    const int local = idx & 131071;
    const int chunk = local >> 14;
    const int e = local & 16383;
    const int n = e >> 6;
    const int kl = (e & 63) ^ ((n & 7) << 3);
    const int k = chunk * 64 + kl;
    const float* Wl = half ? Wl1 : Wl0;
    const float* Wr = half ? Wr1 : Wr0;
    const float v = (k < 256) ? Wl[k * 256 + n] : Wr[(k - 256) * 256 + n];
    (half ? Wt1 : Wt0)[local] = f2bf(v);
}

// ---------------------------------------------------------------------------
// Fully fused SAGE layer:
//   gather+mean(fan src rows) -> swizzled LDS A-tile (k<256 half)
//   -> MFMA chunks 0..3 -> overwrite A-tile with x_tgt rows (k>=256 half)
//   -> MFMA chunks 4..7 -> bias + LayerNorm + ReLU -> bf16 H.
// X: feature table ([*,256] f32 for layer 0, bf16 for layer 1) — both the
// message source and (via tlid) the root features.
// Wt: [8][16384] bf16 swizzled chunk-major (see convert_w2).
// Block: BM targets x 256 cols, 4 waves; wave w owns cols w*64..+64 as
// (BM/16)x4 fragments of mfma_f32_16x16x32_bf16.
// LDS A-tile: [BM][256] bf16, byte(r,c) = r*512 + (c&~63)*2 + ((c&63)*2 ^ ((r&7)<<4)).
// LDS W-tile: [256][64] bf16 per chunk, byte(n,kl) = n*128 + (kl*2 ^ ((n&7)<<4)).
// ---------------------------------------------------------------------------
template <int BM, int FAN, typename XT>
__global__ __launch_bounds__(256, (BM == 64) ? 2 : 3) void fused_sage(
    const XT* __restrict__ X, const int* __restrict__ src,
    const int* __restrict__ tlid, const ushort* __restrict__ Wt,
    const float* __restrict__ bias, const float* __restrict__ g,
    const float* __restrict__ be, ushort* __restrict__ H,
    int M, int fan_rt)
{
    constexpr int MI = BM / 16;
    constexpr int TPW = BM / 4;      // targets per wave
    __shared__ ushort As[BM * 256];  // BM*512 bytes (swizzled image)
    __shared__ ushort Ws[256 * 64];  // 32 KB (swizzled image of one chunk)
    __shared__ float rS[4][BM];
    __shared__ float rQ[4][BM];
    __shared__ int tl[BM];

    f32x4 acc[MI][4] = {};

    const int tid = threadIdx.x;
    const int wave = tid >> 6;
    const int lane = tid & 63;
    const int l15 = lane & 15;
    const int l4 = lane >> 4;
    const long row0 = (long)blockIdx.x * BM;
    const int col0 = wave * 64;
    const int fan = FAN > 0 ? FAN : fan_rt;
    const float inv_fan = 1.0f / (float)fan;

    if (tid < BM) {
        long rr = row0 + tid; if (rr >= M) rr = M - 1;
        tl[tid] = tlid[rr];
    }

    auto stage_ws = [&](int kc8) {
#pragma unroll
        for (int i = 0; i < 8; ++i) {
            const int base = wave * 8192 + i * 1024;   // wave-uniform
            gload16((const char*)Wt + kc8 * 32768 + base + lane * 16,
                    (char*)Ws + base);
        }
    };

    auto do_mfma = [&](int kc) {
#pragma unroll
        for (int ks = 0; ks < 2; ++ks) {
            bf16x8 bfr[4], afr[MI];
#pragma unroll
            for (int ni = 0; ni < 4; ++ni) {
                const int n = col0 + ni * 16 + l15;
                const int byte = n * 128 + ((ks * 64 + l4 * 16) ^ ((n & 7) << 4));
                bfr[ni] = *(const bf16x8*)((const char*)Ws + byte);
            }
#pragma unroll
            for (int mi = 0; mi < MI; ++mi) {
                const int r = mi * 16 + l15;
                const int byte = r * 512 + kc * 128 +
                                 ((ks * 64 + l4 * 16) ^ ((r & 7) << 4));
                afr[mi] = *(const bf16x8*)((const char*)As + byte);
            }
#pragma unroll
            for (int mi = 0; mi < MI; ++mi)
#pragma unroll
                for (int ni = 0; ni < 4; ++ni)
                    acc[mi][ni] = __builtin_amdgcn_mfma_f32_16x16x32_bf16(
                        afr[mi], bfr[ni], acc[mi][ni], 0, 0, 0);
        }
    };

    // Issue W chunk 0 early — its HBM/L2 latency hides under the gather phase.
    stage_ws(0);

    // ---- gather + mean -> As (k<256 half), swizzled ----
    for (int tg = wave * TPW; tg < wave * TPW + TPW; ++tg) {
        long t = row0 + tg; if (t >= M) t = M - 1;
        int myidx = 0;
        if (lane < fan) myidx = src[t * (long)fan + lane];

        float a0 = 0.f, a1 = 0.f, a2 = 0.f, a3 = 0.f;
        auto body = [&](int e) {
            const long s = (long)__shfl(myidx, e, 64);
            if constexpr (sizeof(XT) == 4) {
                const float4 v = *(const float4*)((const float*)X + s * 256 + lane * 4);
                a0 += v.x; a1 += v.y; a2 += v.z; a3 += v.w;
            } else {
                const ushort4 v = *(const ushort4*)((const ushort*)X + s * 256 + lane * 4);
                a0 += bf2f(v.x); a1 += bf2f(v.y); a2 += bf2f(v.z); a3 += bf2f(v.w);
            }
        };
        if constexpr (FAN > 0) {
#pragma unroll
            for (int e = 0; e < FAN; ++e) body(e);
        } else {
            for (int e = 0; e < fan; ++e) body(e);
        }

        ushort4 o;
        o.x = f2bf(a0 * inv_fan); o.y = f2bf(a1 * inv_fan);
        o.z = f2bf(a2 * inv_fan); o.w = f2bf(a3 * inv_fan);
        const int c = lane * 4;
        const int byte = tg * 512 + (c & ~63) * 2 + (((c & 63) * 2) ^ ((tg & 7) << 4));
        *(ushort4*)((char*)As + byte) = o;
    }
    __syncthreads();   // As(k<256) ready; Ws(0) drained (vmcnt(0) at barrier)

    // ---- MFMA chunks 0..3 ----
    for (int kc = 0; kc < 4; ++kc) {
        do_mfma(kc);
        __syncthreads();
        if (kc < 3) { stage_ws(kc + 1); __syncthreads(); }
    }

    // ---- overwrite As with x_tgt rows (k>=256 half), swizzled ----
    stage_ws(4);
    if constexpr (sizeof(XT) == 4) {
#pragma unroll
        for (int it = 0; it < BM / 4; ++it) {
            const int idx = tid + it * 256;
            const int r = idx >> 6, c4 = (idx & 63) * 4;
            const float4 v = *(const float4*)&(
                (const float*)X)[(size_t)tl[r] * 256 + c4];
            ushort4 o;
            o.x = f2bf(v.x); o.y = f2bf(v.y); o.z = f2bf(v.z); o.w = f2bf(v.w);
            const int byte = r * 512 + (c4 & ~63) * 2 + (((c4 & 63) * 2) ^ ((r & 7) << 4));
            *(ushort4*)((char*)As + byte) = o;
        }
    } else {
#pragma unroll
        for (int it = 0; it < BM / 8; ++it) {
            const int idx = tid + it * 256;
            const int r = idx >> 5, c = (idx & 31) * 8;
            const int4 v = *(const int4*)&(
                (const ushort*)X)[(size_t)tl[r] * 256 + c];
            const int byte = r * 512 + (c & ~63) * 2 + (((c & 63) * 2) ^ ((r & 7) << 4));
            *(int4*)((char*)As + byte) = v;
        }
    }
    __syncthreads();

    // ---- MFMA chunks 4..7 ----
    for (int kc = 0; kc < 4; ++kc) {
        do_mfma(kc);
        __syncthreads();
        if (kc < 3) { stage_ws(5 + kc); __syncthreads(); }
    }

    // ---- epilogue: bias, LN stats, normalize, ReLU, bf16 store ----
    float bj[4], gj[4], bej[4];
#pragma unroll
    for (int ni = 0; ni < 4; ++ni) {
        const int c = col0 + ni * 16 + l15;
        bj[ni] = bias[c]; gj[ni] = g[c]; bej[ni] = be[c];
    }

#pragma unroll
    for (int mi = 0; mi < MI; ++mi) {
#pragma unroll
        for (int r = 0; r < 4; ++r) {
            float s = 0.f, q = 0.f;
#pragma unroll
            for (int ni = 0; ni < 4; ++ni) {
                const float v = acc[mi][ni][r] + bj[ni];
                acc[mi][ni][r] = v;
                s += v; q += v * v;
            }
#pragma unroll
            for (int off = 1; off < 16; off <<= 1) {
                s += __shfl_xor(s, off, 64);
                q += __shfl_xor(q, off, 64);
            }
            if (l15 == 0) {
                const int m = mi * 16 + l4 * 4 + r;
                rS[wave][m] = s; rQ[wave][m] = q;
            }
        }
    }
    __syncthreads();

#pragma unroll
    for (int mi = 0; mi < MI; ++mi) {
#pragma unroll
        for (int r = 0; r < 4; ++r) {
            const int m = mi * 16 + l4 * 4 + r;
            if (row0 + m >= M) continue;
            const float s = rS[0][m] + rS[1][m] + rS[2][m] + rS[3][m];
            const float q = rQ[0][m] + rQ[1][m] + rQ[2][m] + rQ[3][m];
            const float mu = s * (1.f / 256.f);
            const float var = q * (1.f / 256.f) - mu * mu;
            const float inv = rsqrtf(var + LN_EPS);
#pragma unroll
            for (int ni = 0; ni < 4; ++ni) {
                float hn = (acc[mi][ni][r] - mu) * inv * gj[ni] + bej[ni];
                hn = fmaxf(hn, 0.f);
                H[(row0 + m) * 256 + col0 + ni * 16 + l15] = f2bf(hn);
            }
        }
    }
}

// ---------------------------------------------------------------------------
// Final FC: out[M,C] = H @ W + b. H bf16, W/b/out f32. Thread per column.
// ---------------------------------------------------------------------------
template <int RB>
__global__ __launch_bounds__(256) void fc_kernel_bf(
    const ushort* __restrict__ Hh, const float* __restrict__ W,
    const float* __restrict__ bias, float* __restrict__ out,
    int M, int C)
{
    const int j = threadIdx.x;
    const long row0 = (long)blockIdx.x * RB;
    if (j >= C) return;

    float acc[RB];
    const float bjv = bias[j];
#pragma unroll
    for (int r = 0; r < RB; ++r) acc[r] = bjv;

    const ushort* Hb = Hh + row0 * 256;
#pragma unroll 4
    for (int k = 0; k < 256; ++k) {
        const float w = W[(long)k * C + j];
#pragma unroll
        for (int r = 0; r < RB; ++r)
            acc[r] = fmaf(bf2f(Hb[r * 256 + k]), w, acc[r]);
    }
#pragma unroll
    for (int r = 0; r < RB; ++r)
        if (row0 + r < M) out[(row0 + r) * C + j] = acc[r];
}

// ---------------------------------------------------------------------------
// Launch
// ---------------------------------------------------------------------------
extern "C" void kernel_launch(void* const* d_in, const int* in_sizes, int n_in,
                              void* d_out, int out_size, void* d_ws, size_t ws_size,
                              hipStream_t stream)
{
    const float* x_feat = (const float*)d_in[0];
    const int*   e0src  = (const int*)d_in[1];
    const int*   tlid0  = (const int*)d_in[3];
    const int*   e1src  = (const int*)d_in[4];
    const int*   tlid1  = (const int*)d_in[6];
    const float* Wl0 = (const float*)d_in[7];
    const float* Wr0 = (const float*)d_in[8];
    const float* b0  = (const float*)d_in[9];
    const float* g0  = (const float*)d_in[10];
    const float* be0 = (const float*)d_in[11];
    const float* Wl1 = (const float*)d_in[12];
    const float* Wr1 = (const float*)d_in[13];
    const float* b1  = (const float*)d_in[14];
    const float* g1  = (const float*)d_in[15];
    const float* be1 = (const float*)d_in[16];
    const float* fcW = (const float*)d_in[17];
    const float* fcb = (const float*)d_in[18];

    const int N1   = in_sizes[3];
    const int fan0 = in_sizes[1] / N1;
    const int N2   = in_sizes[6];
    const int fan1 = in_sizes[4] / N2;
    const int C    = in_sizes[18];

    // Workspace:
    //   Wt0 [8][16384] bf16 swizzled, Wt1 same (256 KB each)
    //   H0 [N1][256] bf16 (23.1 MB), H1 [N2][256] bf16 (2.1 MB)
    char* ws = (char*)d_ws;
    ushort* Wt0 = (ushort*)ws;                         ws += 256 * 512 * 2;
    ushort* Wt1 = (ushort*)ws;                         ws += 256 * 512 * 2;
    ushort* H0  = (ushort*)ws;                         ws += (size_t)N1 * 256 * 2;
    ushort* H1  = (ushort*)ws;

    convert_w2<<<1024, 256, 0, stream>>>(Wl0, Wr0, Wl1, Wr1, Wt0, Wt1);

    // ---- Layer 0 (fused gather+GEMM+LN+ReLU) ----
    if (fan0 == 15)
        fused_sage<64, 15, float><<<(N1 + 63) / 64, 256, 0, stream>>>(
            x_feat, e0src, tlid0, Wt0, b0, g0, be0, H0, N1, fan0);
    else
        fused_sage<64, 0, float><<<(N1 + 63) / 64, 256, 0, stream>>>(
            x_feat, e0src, tlid0, Wt0, b0, g0, be0, H0, N1, fan0);

    // ---- Layer 1 (fused) ----
    if (fan1 == 10)
        fused_sage<32, 10, ushort><<<(N2 + 31) / 32, 256, 0, stream>>>(
            H0, e1src, tlid1, Wt1, b1, g1, be1, H1, N2, fan1);
    else
        fused_sage<32, 0, ushort><<<(N2 + 31) / 32, 256, 0, stream>>>(
            H0, e1src, tlid1, Wt1, b1, g1, be1, H1, N2, fan1);

    // ---- FC ----
    fc_kernel_bf<16><<<(N2 + 15) / 16, 256, 0, stream>>>(
        H1, fcW, fcb, (float*)d_out, N2, C);
}

// Round 6
// 215.355 us; speedup vs baseline: 4.8665x; 1.0937x over previous
//
#include <hip/hip_runtime.h>

#define LN_EPS 1e-5f

typedef __attribute__((ext_vector_type(4))) float f32x4;
typedef __attribute__((ext_vector_type(8))) short bf16x8;

__device__ inline float bf2f(ushort u) {
    union { unsigned u32; float f; } c; c.u32 = (unsigned)u << 16; return c.f;
}
__device__ inline ushort f2bf(float f) {
    union { float f; unsigned u; } c; c.f = f;
    unsigned r = c.u + 0x7FFF + ((c.u >> 16) & 1);   // round-to-nearest-even
    return (ushort)(r >> 16);
}

// ---------------------------------------------------------------------------
// Weights in FRAGMENT ORDER: flat index
//   (((kc*4 + wave)*2 + ks)*4 + ni)*512 + lane*8 + j
// holds logical W^T element (n, k) with
//   n = wave*64 + ni*16 + (lane&15),  k = kc*64 + ks*32 + (lane>>4)*8 + j
//   logical(n,k) = k<256 ? Wl[k][n] : Wr[k-256][n]
// so each wave's MFMA B-fragment load is one coalesced 1KB global load
// (L2-resident, broadcast across blocks) — no LDS staging for W at all.
// ---------------------------------------------------------------------------
__global__ __launch_bounds__(256) void convert_w2(
    const float* __restrict__ Wl0, const float* __restrict__ Wr0,
    const float* __restrict__ Wl1, const float* __restrict__ Wr1,
    ushort* __restrict__ Wf0, ushort* __restrict__ Wf1)
{
    const int idx = blockIdx.x * 256 + threadIdx.x;   // 0 .. 262143
    const int half = idx >> 17;
    const int local = idx & 131071;
    const int j    = local & 7;
    const int lane = (local >> 3) & 63;
    const int ni   = (local >> 9) & 3;
    const int ks   = (local >> 11) & 1;
    const int wv   = (local >> 12) & 3;
    const int kc   = local >> 14;
    const int n = wv * 64 + ni * 16 + (lane & 15);
    const int k = kc * 64 + ks * 32 + (lane >> 4) * 8 + j;
    const float* Wl = half ? Wl1 : Wl0;
    const float* Wr = half ? Wr1 : Wr0;
    const float v = (k < 256) ? Wl[k * 256 + n] : Wr[(k - 256) * 256 + n];
    (half ? Wf1 : Wf0)[local] = f2bf(v);
}

// ---------------------------------------------------------------------------
// Fully fused SAGE layer, minimal-barrier version:
//   gather+mean -> swizzled LDS A-tile (k<256)  | 1 barrier
//   MFMA chunks 0..3 (B-frags straight from L2) | no barriers
//   barrier; overwrite A-tile with x_tgt rows; barrier
//   MFMA chunks 4..7; LN epilogue (1 barrier).
// LDS: As [BM][256] bf16 swizzled + rS/rQ + tl  (~34 KB for BM=64).
// Block: 4 waves; wave w owns output cols w*64..+64.
// ---------------------------------------------------------------------------
template <int BM, int FAN, typename XT>
__global__ __launch_bounds__(256, 3) void fused_sage(
    const XT* __restrict__ X, const int* __restrict__ src,
    const int* __restrict__ tlid, const ushort* __restrict__ Wf,
    const float* __restrict__ bias, const float* __restrict__ g,
    const float* __restrict__ be, ushort* __restrict__ H,
    int M, int fan_rt)
{
    constexpr int MI = BM / 16;
    constexpr int TPW = BM / 4;      // targets per wave
    __shared__ ushort As[BM * 256];  // BM*512 bytes, swizzled image
    __shared__ float rS[4][BM];
    __shared__ float rQ[4][BM];
    __shared__ int tl[BM];

    f32x4 acc[MI][4] = {};

    const int tid = threadIdx.x;
    const int wave = tid >> 6;
    const int lane = tid & 63;
    const int l15 = lane & 15;
    const int l4 = lane >> 4;
    const long row0 = (long)blockIdx.x * BM;
    const int col0 = wave * 64;
    const int fan = FAN > 0 ? FAN : fan_rt;
    const float inv_fan = 1.0f / (float)fan;

    if (tid < BM) {
        long rr = row0 + tid; if (rr >= M) rr = M - 1;
        tl[tid] = tlid[rr];
    }

    // ---- gather + mean -> As (k<256 half), swizzled ----
    for (int tg = wave * TPW; tg < wave * TPW + TPW; ++tg) {
        long t = row0 + tg; if (t >= M) t = M - 1;
        int myidx = 0;
        if (lane < fan) myidx = src[t * (long)fan + lane];

        float a0 = 0.f, a1 = 0.f, a2 = 0.f, a3 = 0.f;
        auto body = [&](int e) {
            const long s = (long)__shfl(myidx, e, 64);
            if constexpr (sizeof(XT) == 4) {
                const float4 v = *(const float4*)((const float*)X + s * 256 + lane * 4);
                a0 += v.x; a1 += v.y; a2 += v.z; a3 += v.w;
            } else {
                const ushort4 v = *(const ushort4*)((const ushort*)X + s * 256 + lane * 4);
                a0 += bf2f(v.x); a1 += bf2f(v.y); a2 += bf2f(v.z); a3 += bf2f(v.w);
            }
        };
        if constexpr (FAN > 0) {
#pragma unroll
            for (int e = 0; e < FAN; ++e) body(e);
        } else {
            for (int e = 0; e < fan; ++e) body(e);
        }

        ushort4 o;
        o.x = f2bf(a0 * inv_fan); o.y = f2bf(a1 * inv_fan);
        o.z = f2bf(a2 * inv_fan); o.w = f2bf(a3 * inv_fan);
        const int c = lane * 4;
        const int byte = tg * 512 + (c & ~63) * 2 + (((c & 63) * 2) ^ ((tg & 7) << 4));
        *(ushort4*)((char*)As + byte) = o;
    }
    __syncthreads();                                   // barrier 1

    // B-fragment load: one coalesced 16B/lane global load (L2-resident).
    auto ldfrag = [&](int kc, int q /*= ks*4+ni*/) -> bf16x8 {
        return *(const bf16x8*)(Wf + (((((kc << 2) + wave) << 1) + (q >> 2)) * 4
                                      + (q & 3)) * 512 + lane * 8);
    };
    auto mfma_chunk = [&](int kc, const bf16x8* bfr /*8: ks*4+ni*/) {
#pragma unroll
        for (int ks = 0; ks < 2; ++ks) {
            bf16x8 afr[MI];
#pragma unroll
            for (int mi = 0; mi < MI; ++mi) {
                const int r = mi * 16 + l15;
                const int byte = r * 512 + kc * 128 +
                                 ((ks * 64 + l4 * 16) ^ ((r & 7) << 4));
                afr[mi] = *(const bf16x8*)((const char*)As + byte);
            }
#pragma unroll
            for (int mi = 0; mi < MI; ++mi)
#pragma unroll
                for (int ni = 0; ni < 4; ++ni)
                    acc[mi][ni] = __builtin_amdgcn_mfma_f32_16x16x32_bf16(
                        afr[mi], bfr[ks * 4 + ni], acc[mi][ni], 0, 0, 0);
        }
    };

    // ---- MFMA chunks 0..3 (no barriers between chunks) ----
#pragma unroll
    for (int kc = 0; kc < 4; ++kc) {
        bf16x8 bfr[8];
#pragma unroll
        for (int q = 0; q < 8; ++q) bfr[q] = ldfrag(kc, q);
        mfma_chunk(kc, bfr);
    }
    __syncthreads();                                   // barrier 2

    // ---- overwrite As with x_tgt rows (k>=256 half), swizzled ----
    if constexpr (sizeof(XT) == 4) {
#pragma unroll
        for (int it = 0; it < BM / 4; ++it) {
            const int idx = tid + it * 256;
            const int r = idx >> 6, c4 = (idx & 63) * 4;
            const float4 v = *(const float4*)&(
                (const float*)X)[(size_t)tl[r] * 256 + c4];
            ushort4 o;
            o.x = f2bf(v.x); o.y = f2bf(v.y); o.z = f2bf(v.z); o.w = f2bf(v.w);
            const int byte = r * 512 + (c4 & ~63) * 2 + (((c4 & 63) * 2) ^ ((r & 7) << 4));
            *(ushort4*)((char*)As + byte) = o;
        }
    } else {
#pragma unroll
        for (int it = 0; it < BM / 8; ++it) {
            const int idx = tid + it * 256;
            const int r = idx >> 5, c = (idx & 31) * 8;
            const int4 v = *(const int4*)&(
                (const ushort*)X)[(size_t)tl[r] * 256 + c];
            const int byte = r * 512 + (c & ~63) * 2 + (((c & 63) * 2) ^ ((r & 7) << 4));
            *(int4*)((char*)As + byte) = v;
        }
    }
    __syncthreads();                                   // barrier 3

    // ---- MFMA chunks 4..7 ----
#pragma unroll
    for (int kc = 0; kc < 4; ++kc) {
        bf16x8 bfr[8];
#pragma unroll
        for (int q = 0; q < 8; ++q) bfr[q] = ldfrag(kc + 4, q);
        mfma_chunk(kc, bfr);
    }

    // ---- epilogue: bias, LN stats, normalize, ReLU, bf16 store ----
    float bj[4], gj[4], bej[4];
#pragma unroll
    for (int ni = 0; ni < 4; ++ni) {
        const int c = col0 + ni * 16 + l15;
        bj[ni] = bias[c]; gj[ni] = g[c]; bej[ni] = be[c];
    }

#pragma unroll
    for (int mi = 0; mi < MI; ++mi) {
#pragma unroll
        for (int r = 0; r < 4; ++r) {
            float s = 0.f, q = 0.f;
#pragma unroll
            for (int ni = 0; ni < 4; ++ni) {
                const float v = acc[mi][ni][r] + bj[ni];
                acc[mi][ni][r] = v;
                s += v; q += v * v;
            }
#pragma unroll
            for (int off = 1; off < 16; off <<= 1) {
                s += __shfl_xor(s, off, 64);
                q += __shfl_xor(q, off, 64);
            }
            if (l15 == 0) {
                const int m = mi * 16 + l4 * 4 + r;
                rS[wave][m] = s; rQ[wave][m] = q;
            }
        }
    }
    __syncthreads();                                   // barrier 4

#pragma unroll
    for (int mi = 0; mi < MI; ++mi) {
#pragma unroll
        for (int r = 0; r < 4; ++r) {
            const int m = mi * 16 + l4 * 4 + r;
            if (row0 + m >= M) continue;
            const float s = rS[0][m] + rS[1][m] + rS[2][m] + rS[3][m];
            const float q = rQ[0][m] + rQ[1][m] + rQ[2][m] + rQ[3][m];
            const float mu = s * (1.f / 256.f);
            const float var = q * (1.f / 256.f) - mu * mu;
            const float inv = rsqrtf(var + LN_EPS);
#pragma unroll
            for (int ni = 0; ni < 4; ++ni) {
                float hn = (acc[mi][ni][r] - mu) * inv * gj[ni] + bej[ni];
                hn = fmaxf(hn, 0.f);
                H[(row0 + m) * 256 + col0 + ni * 16 + l15] = f2bf(hn);
            }
        }
    }
}

// ---------------------------------------------------------------------------
// Final FC: out[M,C] = H @ W + b. H bf16, W/b/out f32. Thread per column.
// ---------------------------------------------------------------------------
template <int RB>
__global__ __launch_bounds__(256) void fc_kernel_bf(
    const ushort* __restrict__ Hh, const float* __restrict__ W,
    const float* __restrict__ bias, float* __restrict__ out,
    int M, int C)
{
    const int j = threadIdx.x;
    const long row0 = (long)blockIdx.x * RB;
    if (j >= C) return;

    float acc[RB];
    const float bjv = bias[j];
#pragma unroll
    for (int r = 0; r < RB; ++r) acc[r] = bjv;

    const ushort* Hb = Hh + row0 * 256;
#pragma unroll 4
    for (int k = 0; k < 256; ++k) {
        const float w = W[(long)k * C + j];
#pragma unroll
        for (int r = 0; r < RB; ++r)
            acc[r] = fmaf(bf2f(Hb[r * 256 + k]), w, acc[r]);
    }
#pragma unroll
    for (int r = 0; r < RB; ++r)
        if (row0 + r < M) out[(row0 + r) * C + j] = acc[r];
}

// ---------------------------------------------------------------------------
// Launch
// ---------------------------------------------------------------------------
extern "C" void kernel_launch(void* const* d_in, const int* in_sizes, int n_in,
                              void* d_out, int out_size, void* d_ws, size_t ws_size,
                              hipStream_t stream)
{
    const float* x_feat = (const float*)d_in[0];
    const int*   e0src  = (const int*)d_in[1];
    const int*   tlid0  = (const int*)d_in[3];
    const int*   e1src  = (const int*)d_in[4];
    const int*   tlid1  = (const int*)d_in[6];
    const float* Wl0 = (const float*)d_in[7];
    const float* Wr0 = (const float*)d_in[8];
    const float* b0  = (const float*)d_in[9];
    const float* g0  = (const float*)d_in[10];
    const float* be0 = (const float*)d_in[11];
    const float* Wl1 = (const float*)d_in[12];
    const float* Wr1 = (const float*)d_in[13];
    const float* b1  = (const float*)d_in[14];
    const float* g1  = (const float*)d_in[15];
    const float* be1 = (const float*)d_in[16];
    const float* fcW = (const float*)d_in[17];
    const float* fcb = (const float*)d_in[18];

    const int N1   = in_sizes[3];
    const int fan0 = in_sizes[1] / N1;
    const int N2   = in_sizes[6];
    const int fan1 = in_sizes[4] / N2;
    const int C    = in_sizes[18];

    // Workspace: Wf0/Wf1 fragment-ordered bf16 (256 KB each), H0, H1.
    char* ws = (char*)d_ws;
    ushort* Wf0 = (ushort*)ws;                         ws += 256 * 512 * 2;
    ushort* Wf1 = (ushort*)ws;                         ws += 256 * 512 * 2;
    ushort* H0  = (ushort*)ws;                         ws += (size_t)N1 * 256 * 2;
    ushort* H1  = (ushort*)ws;

    convert_w2<<<1024, 256, 0, stream>>>(Wl0, Wr0, Wl1, Wr1, Wf0, Wf1);

    // ---- Layer 0 (fused gather+GEMM+LN+ReLU) ----
    if (fan0 == 15)
        fused_sage<64, 15, float><<<(N1 + 63) / 64, 256, 0, stream>>>(
            x_feat, e0src, tlid0, Wf0, b0, g0, be0, H0, N1, fan0);
    else
        fused_sage<64, 0, float><<<(N1 + 63) / 64, 256, 0, stream>>>(
            x_feat, e0src, tlid0, Wf0, b0, g0, be0, H0, N1, fan0);

    // ---- Layer 1 (fused) ----
    if (fan1 == 10)
        fused_sage<32, 10, ushort><<<(N2 + 31) / 32, 256, 0, stream>>>(
            H0, e1src, tlid1, Wf1, b1, g1, be1, H1, N2, fan1);
    else
        fused_sage<32, 0, ushort><<<(N2 + 31) / 32, 256, 0, stream>>>(
            H0, e1src, tlid1, Wf1, b1, g1, be1, H1, N2, fan1);

    // ---- FC ----
    fc_kernel_bf<16><<<(N2 + 15) / 16, 256, 0, stream>>>(
        H1, fcW, fcb, (float*)d_out, N2, C);
}